// Round 12
// baseline (340.197 us; speedup 1.0000x reference)
//
#include <hip/hip_runtime.h>

#define KDIM 4096
#define NDIM 4096
#define BM 256
#define BN 256
#define BK 128            // K bytes (int8) per tile
#define NTILE (KDIM / BK) // 32
#define BBUF 32768        // B tile: 256 rows x 128 B

using i32x4 = __attribute__((ext_vector_type(4))) int;
using i32x16 = __attribute__((ext_vector_type(16))) int;

__device__ __forceinline__ void g2l16(const void* g, void* l) {
  __builtin_amdgcn_global_load_lds(
      (const __attribute__((address_space(1))) void*)g,
      (__attribute__((address_space(3))) void*)l,
      16, 0, 0);
}

// ---------------- detect: weight buffer int32-expanded (flag=1) or raw int8 (flag=0)?
__global__ void w8l_detect(const int* __restrict__ w32, int* __restrict__ flag) {
  __shared__ int s;
  const int t = threadIdx.x;
  if (t == 0) s = 1;
  __syncthreads();
  bool oob = false;
#pragma unroll
  for (int i = 0; i < 16; ++i) {
    int v = w32[t * 16 + i];
    if (v < -128 || v > 127) oob = true;
  }
  if (oob) atomicAnd(&s, 0);
  __syncthreads();
  if (t == 0) *flag = s;
}

// ---------------- pack int32 weights to int8 (no-op when flag==0)
__global__ void w8l_pack(const void* __restrict__ wsrc, const int* __restrict__ flag,
                         signed char* __restrict__ wq) {
  if (*flag == 0) return;
  const int t = blockIdx.x * blockDim.x + threadIdx.x;
  const int4* s = (const int4*)wsrc;
  int4 a = s[t * 4 + 0], b = s[t * 4 + 1], c = s[t * 4 + 2], d = s[t * 4 + 3];
  int4 o;
  o.x = (a.x & 255) | ((a.y & 255) << 8) | ((a.z & 255) << 16) | ((a.w & 255) << 24);
  o.y = (b.x & 255) | ((b.y & 255) << 8) | ((b.z & 255) << 16) | ((b.w & 255) << 24);
  o.z = (c.x & 255) | ((c.y & 255) << 8) | ((c.z & 255) << 16) | ((c.w & 255) << 24);
  o.w = (d.x & 255) | ((d.y & 255) << 8) | ((d.z & 255) << 16) | ((d.w & 255) << 24);
  ((int4*)wq)[t] = o;
}

// ---------------- quantize activations INTO MFMA FRAGMENT CELL LAYOUT (r10-verified):
// A'[cell], cell = (mb*256 + kc)*16 + r  (mb=m>>4, kc=k>>4, r=m&15), 16 B per cell.
__global__ void w8l_quant(const float* __restrict__ x, const float* __restrict__ xs,
                          signed char* __restrict__ aq) {
  const int t = blockIdx.x * blockDim.x + threadIdx.x;  // cell index
  const float s = *xs;
  const int r = t & 15;
  const int kc = (t >> 4) & 255;
  const int mb = t >> 12;
  const float4* x4 = (const float4*)(x + (size_t)(mb * 16 + r) * KDIM + kc * 16);
  int4 o;
  int* op = (int*)&o;
#pragma unroll
  for (int q = 0; q < 4; ++q) {
    float4 f = x4[q];
    int v0 = __float2int_rn(f.x / s);
    int v1 = __float2int_rn(f.y / s);
    int v2 = __float2int_rn(f.z / s);
    int v3 = __float2int_rn(f.w / s);
    v0 = v0 < -128 ? -128 : (v0 > 127 ? 127 : v0);
    v1 = v1 < -128 ? -128 : (v1 > 127 ? 127 : v1);
    v2 = v2 < -128 ? -128 : (v2 > 127 ? 127 : v2);
    v3 = v3 < -128 ? -128 : (v3 > 127 ? 127 : v3);
    op[q] = (v0 & 255) | ((v1 & 255) << 8) | ((v2 & 255) << 16) | ((v3 & 255) << 24);
  }
  ((int4*)aq)[t] = o;
}

// ---------------- 256x256 i8 GEMM, 4 waves (2x2, 128x128 each), 32x32x32 MFMA.
// LDS holds ONLY B (tri-buffered, 96 KiB): per tile 64 KB read + 32 KB write —
// 2.7x less DS traffic than r4-r11 (the additive-model binding term).
// A comes from A' fragment-layout VMEM loads (1 KB coalesced), issued one FULL
// tile ahead into E/O register sets (VMEM pipe overlaps MFMA; 11-round evidence).
// Only hand wait: one vmcnt(0)/tile targeting loads >=1 tile old (~zero stall).
// B swizzle (r7/r11-verified, 0 conflicts): LDS(r,slot) = chunk(slot ^ s(r)),
// s(r) = (r ^ (r>>3)) & 7.
__global__ __launch_bounds__(256, 1) void w8l_gemm(
    const signed char* __restrict__ Ap,
    const signed char* __restrict__ Wraw, const signed char* __restrict__ Wpk,
    const int* __restrict__ flag,
    const float* __restrict__ scale, const float* __restrict__ xscale,
    const float* __restrict__ bias, float* __restrict__ out, int nbn) {
  __shared__ signed char lds[3 * BBUF];  // 96 KiB, B only

  const signed char* __restrict__ Wq = (*flag) ? Wpk : Wraw;

  const int tid = threadIdx.x;
  const int lane = tid & 63;
  const int wid = tid >> 6;  // 0..3
  const int wr = wid >> 1;   // 0..1 (128-row half)
  const int wc = wid & 1;    // 0..1 (128-col half)
  const int l31 = lane & 31;
  const int l5 = lane >> 5;  // 0..1 k-half of chunk pair

  // XCD-aware bijective swizzle (grid = 512, divisible by 8)
  const int nwg = gridDim.x;
  const int cpx = nwg >> 3;
  const int bid = blockIdx.x;
  const int swz = (bid & 7) * cpx + (bid >> 3);
  const int bm = swz / nbn, bn = swz % nbn;
  const int m0 = bm * BM, n0 = bn * BN;

  // ---- B staging: one g2l16 issue = 256 thr x 16 B = 4 KB = 32 rows x 128 B.
  // s(r_in + 32u) = s(r_in) ^ (u&1 ? 4 : 0)  -> two source pointers.
  const unsigned r_in = (unsigned)tid >> 3;  // 0..31
  const unsigned c16 = (unsigned)tid & 7;
  const unsigned s_r = (r_in ^ (r_in >> 3)) & 7u;
  const signed char* wgp0 = Wq + (size_t)(n0 + r_in) * KDIM + ((c16 ^ s_r) << 4);
  const signed char* wgp1 = Wq + (size_t)(n0 + r_in) * KDIM + ((c16 ^ s_r ^ 4u) << 4);
  const unsigned ldsoff = (unsigned)tid * 16u;

#define ISSUE_B(t, buf)                                                       \
  do {                                                                        \
    const size_t koff_ = (size_t)(t) * BK;                                    \
    signed char* lb_ = lds + (unsigned)(buf) * (unsigned)BBUF + ldsoff;       \
    _Pragma("unroll") for (int u = 0; u < 8; ++u) {                           \
      const signed char* gp_ = (u & 1) ? wgp1 : wgp0;                         \
      g2l16(gp_ + (size_t)(u * 32) * KDIM + koff_, lb_ + u * 4096);           \
    }                                                                         \
  } while (0)

  // ---- A' direct loads: frag (ks, mi) of tile t:
  // addr = base + mi*131072 + t*2048 + ks*512, base has per-lane mb/hi/row.
  const signed char* aglp = Ap +
      (size_t)((m0 >> 4) + wr * 8 + (l31 >> 4)) * 65536 +
      (size_t)l5 * 256 + (size_t)(l31 & 15) * 16;

#define LOAD_A(dst, t)                                                        \
  _Pragma("unroll") for (int ks = 0; ks < 4; ++ks)                            \
      _Pragma("unroll") for (int mi = 0; mi < 4; ++mi)                        \
          dst[ks][mi] = *(const i32x4*)(aglp + (size_t)mi * 131072 +          \
                                        (size_t)(t) * 2048 + ks * 512);

  // ---- B frag reads (32x32x32): row r = wc*128 + nj*32 + l31,
  // chunk = 2*ks + l5, slot = chunk ^ s(r)
#define RD_B(dst, base, ks)                                                   \
  _Pragma("unroll") for (int nj = 0; nj < 4; ++nj) {                          \
    const int r_ = wc * 128 + nj * 32 + l31;                                  \
    const int sx_ = (r_ ^ (r_ >> 3)) & 7;                                     \
    dst[nj] = *(const i32x4*)((base) + r_ * 128 +                             \
                              ((((ks) * 2 + l5) ^ sx_) << 4));                \
  }

#define SB __builtin_amdgcn_sched_barrier(0)

#define MFMA16(a4, b4)                                                        \
  __builtin_amdgcn_s_setprio(1);                                              \
  _Pragma("unroll") for (int mi = 0; mi < 4; ++mi)                            \
      _Pragma("unroll") for (int nj = 0; nj < 4; ++nj)                        \
          acc[mi][nj] = __builtin_amdgcn_mfma_i32_32x32x32_i8(                \
              a4[mi], b4[nj], acc[mi][nj], 0, 0, 0);                          \
  __builtin_amdgcn_s_setprio(0);

  i32x16 acc[4][4] = {};
  i32x4 aE[4][4], aO[4][4], b0[4], b1[4], b2[4];

  // one tile: AC = current A regs (consumed), AN = next-tile A regs (loaded)
#define BODY(t, AC, AN)                                                       \
  do {                                                                        \
    asm volatile("s_waitcnt vmcnt(0)" ::: "memory"); /* >=1-tile-old loads */ \
    __builtin_amdgcn_s_barrier();                                             \
    SB;                                                                       \
    if ((t) + 2 < NTILE) ISSUE_B((t) + 2, ((t) + 2) % 3);                     \
    SB;                                                                       \
    if ((t) + 1 < NTILE) LOAD_A(AN, (t) + 1);                                 \
    SB;                                                                       \
    const signed char* base_ = lds + (unsigned)((t) % 3) * (unsigned)BBUF;    \
    RD_B(b0, base_, 0);                                                       \
    RD_B(b1, base_, 1);                                                       \
    RD_B(b2, base_, 2);                                                       \
    SB;                                                                       \
    MFMA16(AC[0], b0);                                                        \
    SB;                                                                       \
    RD_B(b0, base_, 3); /* reuse b0; lands under the next two clusters */     \
    SB;                                                                       \
    MFMA16(AC[1], b1);                                                        \
    SB;                                                                       \
    MFMA16(AC[2], b2);                                                        \
    SB;                                                                       \
    MFMA16(AC[3], b0);                                                        \
    SB;                                                                       \
  } while (0)

  // prologue: B(0), B(1) staged; A(0) in flight. First BODY's vmcnt(0) drains.
  ISSUE_B(0, 0);
  ISSUE_B(1, 1);
  SB;
  LOAD_A(aE, 0);
  SB;

#pragma unroll 1
  for (int kt = 0; kt < NTILE; kt += 2) {
    BODY(kt, aE, aO);
    BODY(kt + 1, aO, aE);
  }

  // epilogue: 32x32 C/D layout col=lane&31, row=(reg&3)+8*(reg>>2)+4*(lane>>5)
  // [m74/m101-verified, dtype-independent; r7/r11-passed code]
  const float cs = scale[0] * xscale[0];
#pragma unroll
  for (int nj = 0; nj < 4; ++nj) {
    const int n = n0 + wc * 128 + nj * 32 + l31;
    const float bj = bias[n];
#pragma unroll
    for (int mi = 0; mi < 4; ++mi) {
      const int mbase = m0 + wr * 128 + mi * 32 + l5 * 4;
#pragma unroll
      for (int r = 0; r < 16; ++r) {
        const int m = mbase + (r & 3) + 8 * (r >> 2);
        out[(size_t)m * NDIM + n] = (float)acc[mi][nj][r] * cs + bj;
      }
    }
  }
#undef ISSUE_B
#undef LOAD_A
#undef RD_B
#undef MFMA16
#undef BODY
#undef SB
}

extern "C" void kernel_launch(void* const* d_in, const int* in_sizes, int n_in,
                              void* d_out, int out_size, void* d_ws, size_t ws_size,
                              hipStream_t stream) {
  const float* x = (const float*)d_in[0];
  const void* w = d_in[1];
  const float* scale = (const float*)d_in[2];
  const float* xscale = (const float*)d_in[3];
  const float* bias = (const float*)d_in[4];
  float* out = (float*)d_out;

  const int M = in_sizes[0] / KDIM;  // 8192

  int* flag = (int*)d_ws;
  signed char* wq = (signed char*)d_ws + 256;
  signed char* aq = wq + (size_t)NDIM * KDIM;  // A' fragment layout, M*K bytes

  const size_t need = 256 + (size_t)NDIM * KDIM + (size_t)M * KDIM;
  if (ws_size < need) return;

  w8l_detect<<<1, 256, 0, stream>>>((const int*)w, flag);
  w8l_pack<<<(NDIM * KDIM / 16) / 256, 256, 0, stream>>>(w, flag, wq);
  w8l_quant<<<(M * KDIM / 16) / 256, 256, 0, stream>>>(x, xscale, aq);

  const int nbn = NDIM / BN;  // 16
  w8l_gemm<<<(M / BM) * nbn, 256, 0, stream>>>(
      aq, (const signed char*)w, wq, flag, scale, xscale, bias, out, nbn);
}